// Round 12
// baseline (344.745 us; speedup 1.0000x reference)
//
#include <hip/hip_runtime.h>

#define NT 256

typedef float f2 __attribute__((ext_vector_type(2)));

// 4-bit bit-reversal (involution)
constexpr int br4(int i) {
    return ((i & 1) << 3) | ((i & 2) << 1) | ((i & 4) >> 1) | ((i & 8) >> 3);
}

// W_32^j = e^{-2*pi*i*j/32}
__device__ constexpr float W32C[16] = {
    1.0f,                0.980785280403230f,  0.923879532511287f,  0.831469612302545f,
    0.707106781186548f,  0.555570233019602f,  0.382683432365090f,  0.195090322016128f,
    0.0f,               -0.195090322016128f, -0.382683432365090f, -0.555570233019602f,
   -0.707106781186548f, -0.831469612302545f, -0.923879532511287f, -0.980785280403230f};
__device__ constexpr float W32S[16] = {
   -0.0f,               -0.195090322016128f, -0.382683432365090f, -0.555570233019602f,
   -0.707106781186548f, -0.831469612302545f, -0.923879532511287f, -0.980785280403230f,
   -1.0f,               -0.980785280403230f, -0.923879532511287f, -0.831469612302545f,
   -0.707106781186548f, -0.555570233019602f, -0.382683432365090f, -0.195090322016128f};

// One-instruction half-wave exchange: a.hi <-> b.lo  (VALU crosslane, not DS pipe)
__device__ __forceinline__ void pl32swap(float& a, float& b) {
    asm("v_permlane32_swap_b32 %0, %1" : "+v"(a), "+v"(b));
}

__device__ __forceinline__ f2 cmulf(f2 a, f2 b) {
    return (f2){a.x * b.x - a.y * b.y, a.x * b.y + a.y * b.x};
}
__device__ __forceinline__ f2 csqrf(f2 a) {
    return (f2){a.x * a.x - a.y * a.y, 2.0f * a.x * a.y};
}

// In-register 16-pt radix-2 DIF FFT (pk-friendly). Output: v[r] = X[br4(r)].
__device__ __forceinline__ void fft16(f2 (&v)[16]) {
#pragma unroll
    for (int s = 8; s >= 1; s >>= 1) {
#pragma unroll
        for (int base = 0; base < 16; base += 2 * s) {
#pragma unroll
            for (int j = 0; j < s; ++j) {
                f2 u = v[base + j];
                f2 w = v[base + j + s];
                f2 d = u - w;                       // v_pk_add/sub
                v[base + j] = u + w;
                const int ti = j * (8 / s);         // W_16^ti = W_32^(2*ti)
                if (ti == 0)
                    v[base + j + s] = d;
                else if (ti == 4)                   // * -i
                    v[base + j + s] = (f2){d.y, -d.x};
                else {
                    const f2 wa = {W32C[2 * ti], W32S[2 * ti]};
                    const f2 wb = {-W32S[2 * ti], W32C[2 * ti]};
                    v[base + j + s] = d.x * wa + d.y * wb;   // cmul, 2 pk ops
                }
            }
        }
    }
}

// Distributed 32-pt FFT across lane-pair (lane, lane^32) via permlane32_swap,
// with the high-half twiddle FUSED into the D-path. R10-hardware-verified.
// Entry: reg r holds y[r + 16*b5]. Exit: reg r holds Y[2*br4(r) + b5].
__device__ __forceinline__ void fft32d(f2 (&v)[16], const f2 (&cwA)[8], const f2 (&cwB)[8]) {
#pragma unroll
    for (int p = 0; p < 16; p += 2) {
        float ax = v[p].x,     ay = v[p].y;
        float bx = v[p + 1].x, by = v[p + 1].y;
        pl32swap(ax, bx);
        pl32swap(ay, by);
        f2 A = (f2){ax, ay};     // {y_p (lo), y_{p+1} (hi)}
        f2 B = (f2){bx, by};     // {y_{p+16} (lo), y_{p+17} (hi)}
        f2 S = A + B;
        f2 D = A - B;
        f2 Dt = D.x * cwA[p >> 1] + D.y * cwB[p >> 1];   // fused hi-twiddle
        float sx = S.x, sy = S.y, dx = Dt.x, dy = Dt.y;
        pl32swap(sx, dx);
        pl32swap(sy, dy);
        v[p]     = (f2){sx, sy};
        v[p + 1] = (f2){dx, dy};
    }
    fft16(v);
}

__global__ __launch_bounds__(NT) void hole_fft_kernel(
    const float* __restrict__ gh, const float* __restrict__ gr, const float* __restrict__ gt,
    float* __restrict__ out)
{
    // XOR-column layout (R5/R8-verified, 0 conflicts): exactly 8 KiB/wave ->
    // 32768 B/block -> 5 blocks/CU (padded layout's 33792 B allowed only 4).
    __shared__ f2 lds[4 * 1024];

    const int tid  = threadIdx.x;
    const int wv   = tid >> 6;
    const int lane = tid & 63;
    const int b5   = lane >> 5;
    const int tau  = lane & 31;
    const bool hi  = (b5 != 0);
    const bool fix0 = (lane == 0);   // only lane 0 needs the rs fixup (R7-verified)

    const int pairIdx = blockIdx.x * 4 + wv;
    const int row0 = pairIdx * 2, row1 = row0 + 1;

    // XOR transpose addressing: elem(row,col) at byte 256*row + 8*(row^col)
    //   write G[tau][k2], k2=2*br4(r)+b5: (264*tau ^ 8*b5) ^ (br4(r)<<4)
    //   read  G[k+16*b5][tau]:            (4224*b5 ^ 8*tau) ^ (264*k)
    char* ldsW = (char*)lds + (wv << 13);
    const int wbyte = (264 * tau) ^ (b5 << 3);
    const int rbyte = (4224 * b5) ^ (tau << 3);

    const int gofs = tau + (b5 << 9);          // element n = gofs + 32*k
    const int pl   = (tau == 0) ? lane : (((lane & 32) ^ 32) | (32 - tau));  // f<->-f partner

    // fused butterfly twiddle table: cw[j] = W32^{2j} on lanes<32, W32^{2j+1} on lanes>=32
    f2 cwA[8], cwB[8];
#pragma unroll
    for (int j = 0; j < 8; ++j) {
        cwA[j] = hi ? (f2){W32C[2 * j + 1], W32S[2 * j + 1]}
                    : (f2){W32C[2 * j],     W32S[2 * j]};
        cwB[j] = (f2){-cwA[j].y, cwA[j].x};
    }

    // dual-form twiddle tables for W_1024^{tau*k2}, k2=2m+b5
    f2 TA[8], TB[8], ThA, ThB;
    {
        float rev = -(float)tau * (1.0f / 1024.0f);   // revolutions (v_cos/v_sin input)
        f2 w  = (f2){__builtin_amdgcn_cosf(rev), __builtin_amdgcn_sinf(rev)};
        f2 w2 = csqrf(w);
        TA[0] = hi ? w : (f2){1.0f, 0.0f};
#pragma unroll
        for (int j = 1; j < 8; ++j) TA[j] = cmulf(TA[j - 1], w2);
        ThA = csqrf(csqrf(csqrf(w2)));                // w^16
#pragma unroll
        for (int j = 0; j < 8; ++j) TB[j] = (f2){-TA[j].y, TA[j].x};
        ThB = (f2){-ThA.y, ThA.x};
    }

    const float* pz0 = gr + (size_t)row0 * 1024 + gofs;
    const float* pz1 = gr + (size_t)row1 * 1024 + gofs;
    const float* px0 = gh + (size_t)row0 * 1024 + gofs;
    const float* px1 = gt + (size_t)row0 * 1024 + gofs;
    const float* py0 = gh + (size_t)row1 * 1024 + gofs;
    const float* py1 = gt + (size_t)row1 * 1024 + gofs;

    f2 z[16], x[16];

    // issue Z and X0 loads up front (latency hidden under Z's FFT)
#pragma unroll
    for (int k = 0; k < 16; ++k) z[k] = (f2){pz0[k * 32], pz1[k * 32]};
#pragma unroll
    for (int k = 0; k < 16; ++k) x[k] = (f2){px0[k * 32], px1[k * 32]};

    // ================= Z = FFT(r0 + i r1) =================
    fft32d(z, cwA, cwB);
#pragma unroll
    for (int rr = 0; rr < 16; ++rr) {               // twiddle W_1024^{tau*k2}
        const int m = br4(rr);
        f2 v = z[rr];
        if (m < 8) {
            z[rr] = v.x * TA[m] + v.y * TB[m];
        } else {
            f2 u = v.x * TA[m - 8] + v.y * TB[m - 8];
            z[rr] = u.x * ThA + u.y * ThB;
        }
    }
    __builtin_amdgcn_wave_barrier();
#pragma unroll
    for (int rr = 0; rr < 16; ++rr)
        *(f2*)(ldsW + (wbyte ^ (br4(rr) << 4))) = z[rr];
    __builtin_amdgcn_wave_barrier();
#pragma unroll
    for (int k = 0; k < 16; ++k)
        z[k] = *(const f2*)(ldsW + (rbyte ^ (264 * k)));
    fft32d(z, cwA, cwB);                             // z[rr] = Z at f = 32*(2*br4(rr)+b5)+tau

    // ================= X0 = FFT(h0 + i t0) =================
    fft32d(x, cwA, cwB);
#pragma unroll
    for (int rr = 0; rr < 16; ++rr) {
        const int m = br4(rr);
        f2 v = x[rr];
        if (m < 8) {
            x[rr] = v.x * TA[m] + v.y * TB[m];
        } else {
            f2 u = v.x * TA[m - 8] + v.y * TB[m - 8];
            x[rr] = u.x * ThA + u.y * ThB;
        }
    }
    __builtin_amdgcn_wave_barrier();
#pragma unroll
    for (int rr = 0; rr < 16; ++rr)
        *(f2*)(ldsW + (wbyte ^ (br4(rr) << 4))) = x[rr];
    __builtin_amdgcn_wave_barrier();
#pragma unroll
    for (int k = 0; k < 16; ++k)
        x[k] = *(const f2*)(ldsW + (rbyte ^ (264 * k)));
    fft32d(x, cwA, cwB);

    // score0 = sum_f 2*im*Z.x - dm*Z.y   (Z lane-local; identity R7-verified)
    float acc0 = 0.0f;
#pragma unroll
    for (int rr = 0; rr < 16; ++rr) {
        const int rq = 15 - rr;
        const int rs = br4((16 - br4(rr)) & 15);
        float fx = __shfl(x[rq].x, pl, 64);
        float fy = __shfl(x[rq].y, pl, 64);
        fx = fix0 ? x[rs].x : fx;
        fy = fix0 ? x[rs].y : fy;
        float im = x[rr].x * fy + x[rr].y * fx;                       // Im(X_f X_-f)
        float dm = fmaf(x[rr].x, x[rr].x, x[rr].y * x[rr].y)
                 - fmaf(fx, fx, fy * fy);                             // |X_f|^2-|X_-f|^2
        acc0 = fmaf(2.0f * im, z[rr].x, acc0);
        acc0 = fmaf(-dm,       z[rr].y, acc0);
    }

    // ================= X1 = FFT(h1 + i t1), reusing x registers =================
#pragma unroll
    for (int k = 0; k < 16; ++k) x[k] = (f2){py0[k * 32], py1[k * 32]};

    fft32d(x, cwA, cwB);
#pragma unroll
    for (int rr = 0; rr < 16; ++rr) {
        const int m = br4(rr);
        f2 v = x[rr];
        if (m < 8) {
            x[rr] = v.x * TA[m] + v.y * TB[m];
        } else {
            f2 u = v.x * TA[m - 8] + v.y * TB[m - 8];
            x[rr] = u.x * ThA + u.y * ThB;
        }
    }
    __builtin_amdgcn_wave_barrier();
#pragma unroll
    for (int rr = 0; rr < 16; ++rr)
        *(f2*)(ldsW + (wbyte ^ (br4(rr) << 4))) = x[rr];
    __builtin_amdgcn_wave_barrier();
#pragma unroll
    for (int k = 0; k < 16; ++k)
        x[k] = *(const f2*)(ldsW + (rbyte ^ (264 * k)));
    fft32d(x, cwA, cwB);

    // score1 = sum_f 2*im*Z.y + dm*Z.x
    float acc1 = 0.0f;
#pragma unroll
    for (int rr = 0; rr < 16; ++rr) {
        const int rq = 15 - rr;
        const int rs = br4((16 - br4(rr)) & 15);
        float fx = __shfl(x[rq].x, pl, 64);
        float fy = __shfl(x[rq].y, pl, 64);
        fx = fix0 ? x[rs].x : fx;
        fy = fix0 ? x[rs].y : fy;
        float im = x[rr].x * fy + x[rr].y * fx;
        float dm = fmaf(x[rr].x, x[rr].x, x[rr].y * x[rr].y)
                 - fmaf(fx, fx, fy * fy);
        acc1 = fmaf(2.0f * im, z[rr].y, acc1);
        acc1 = fmaf(dm,        z[rr].x, acc1);
    }

    // cross-32 reduce of BOTH accs with one swap: lane0 -> row0, lane32 -> row1
    pl32swap(acc0, acc1);
    float s = acc0 + acc1;
#pragma unroll
    for (int off = 16; off > 0; off >>= 1)
        s += __shfl_xor(s, off, 64);
    if (tau == 0)
        out[row0 + b5] = s * (1.0f / 4096.0f);

    (void)hi;
}

extern "C" void kernel_launch(void* const* d_in, const int* in_sizes, int n_in,
                              void* d_out, int out_size, void* d_ws, size_t ws_size,
                              hipStream_t stream) {
    const float* h = (const float*)d_in[0];
    const float* r = (const float*)d_in[1];
    const float* t = (const float*)d_in[2];
    float* out = (float*)d_out;
    int nblocks = out_size / 8;   // 4 row-pairs per block
    hipLaunchKernelGGL(hole_fft_kernel, dim3(nblocks), dim3(NT), 0, stream,
                       h, r, t, out);
}

// Round 13
// 314.571 us; speedup vs baseline: 1.0959x; 1.0959x over previous
//
#include <hip/hip_runtime.h>

#define NT 128   // 2 waves/block: 16896 B LDS/block -> 9 blocks/CU = 18 waves (vs 16 at NT=256)

typedef float f2 __attribute__((ext_vector_type(2)));

// 4-bit bit-reversal (involution)
constexpr int br4(int i) {
    return ((i & 1) << 3) | ((i & 2) << 1) | ((i & 4) >> 1) | ((i & 8) >> 3);
}

// W_32^j = e^{-2*pi*i*j/32}
__device__ constexpr float W32C[16] = {
    1.0f,                0.980785280403230f,  0.923879532511287f,  0.831469612302545f,
    0.707106781186548f,  0.555570233019602f,  0.382683432365090f,  0.195090322016128f,
    0.0f,               -0.195090322016128f, -0.382683432365090f, -0.555570233019602f,
   -0.707106781186548f, -0.831469612302545f, -0.923879532511287f, -0.980785280403230f};
__device__ constexpr float W32S[16] = {
   -0.0f,               -0.195090322016128f, -0.382683432365090f, -0.555570233019602f,
   -0.707106781186548f, -0.831469612302545f, -0.923879532511287f, -0.980785280403230f,
   -1.0f,               -0.980785280403230f, -0.923879532511287f, -0.831469612302545f,
   -0.707106781186548f, -0.555570233019602f, -0.382683432365090f, -0.195090322016128f};

// One-instruction half-wave exchange: a.hi <-> b.lo  (VALU crosslane, not DS pipe)
__device__ __forceinline__ void pl32swap(float& a, float& b) {
    asm("v_permlane32_swap_b32 %0, %1" : "+v"(a), "+v"(b));
}

__device__ __forceinline__ f2 cmulf(f2 a, f2 b) {
    return (f2){a.x * b.x - a.y * b.y, a.x * b.y + a.y * b.x};
}
__device__ __forceinline__ f2 csqrf(f2 a) {
    return (f2){a.x * a.x - a.y * a.y, 2.0f * a.x * a.y};
}

// In-register 16-pt radix-2 DIF FFT (pk-friendly). Output: v[r] = X[br4(r)].
__device__ __forceinline__ void fft16(f2 (&v)[16]) {
#pragma unroll
    for (int s = 8; s >= 1; s >>= 1) {
#pragma unroll
        for (int base = 0; base < 16; base += 2 * s) {
#pragma unroll
            for (int j = 0; j < s; ++j) {
                f2 u = v[base + j];
                f2 w = v[base + j + s];
                f2 d = u - w;                       // v_pk_add/sub
                v[base + j] = u + w;
                const int ti = j * (8 / s);         // W_16^ti = W_32^(2*ti)
                if (ti == 0)
                    v[base + j + s] = d;
                else if (ti == 4)                   // * -i
                    v[base + j + s] = (f2){d.y, -d.x};
                else {
                    const f2 wa = {W32C[2 * ti], W32S[2 * ti]};
                    const f2 wb = {-W32S[2 * ti], W32C[2 * ti]};
                    v[base + j + s] = d.x * wa + d.y * wb;   // cmul, 2 pk ops
                }
            }
        }
    }
}

// Distributed 32-pt FFT across lane-pair (lane, lane^32) via permlane32_swap,
// with the high-half twiddle FUSED into the D-path. R10-hardware-verified.
// Entry: reg r holds y[r + 16*b5]. Exit: reg r holds Y[2*br4(r) + b5].
__device__ __forceinline__ void fft32d(f2 (&v)[16], const f2 (&cwA)[8], const f2 (&cwB)[8]) {
#pragma unroll
    for (int p = 0; p < 16; p += 2) {
        float ax = v[p].x,     ay = v[p].y;
        float bx = v[p + 1].x, by = v[p + 1].y;
        pl32swap(ax, bx);
        pl32swap(ay, by);
        f2 A = (f2){ax, ay};     // {y_p (lo), y_{p+1} (hi)}
        f2 B = (f2){bx, by};     // {y_{p+16} (lo), y_{p+17} (hi)}
        f2 S = A + B;
        f2 D = A - B;
        f2 Dt = D.x * cwA[p >> 1] + D.y * cwB[p >> 1];   // fused hi-twiddle
        float sx = S.x, sy = S.y, dx = Dt.x, dy = Dt.y;
        pl32swap(sx, dx);
        pl32swap(sy, dy);
        v[p]     = (f2){sx, sy};
        v[p + 1] = (f2){dx, dy};
    }
    fft16(v);
}

__global__ __launch_bounds__(NT) void hole_fft_kernel(
    const float* __restrict__ gh, const float* __restrict__ gr, const float* __restrict__ gt,
    float* __restrict__ out)
{
    __shared__ f2 lds[2 * 32 * 33];   // padded stride-33 rows: 8448 B/wave, 2 waves

    const int tid  = threadIdx.x;
    const int wv   = tid >> 6;
    const int lane = tid & 63;
    const int b5   = lane >> 5;
    const int tau  = lane & 31;
    const bool hi  = (b5 != 0);
    const bool fix0 = (lane == 0);   // only lane 0 needs the rs fixup (R7-verified)

    const int pairIdx = blockIdx.x * 2 + wv;
    const int row0 = pairIdx * 2, row1 = row0 + 1;

    // padded transpose addressing: elem(row,col) at byte 264*row + 8*col (all-imm offsets)
    char* ldsB = (char*)lds + wv * 8448;
    char* wp   = ldsB + 264 * tau + 8 * b5;    // + 16*br4(rr) imm
    char* rp_  = ldsB + 4224 * b5 + 8 * tau;   // + 264*k imm

    const int gofs = tau + (b5 << 9);          // element n = gofs + 32*k
    const int pl   = (tau == 0) ? lane : (((lane & 32) ^ 32) | (32 - tau));  // f<->-f partner

    // fused butterfly twiddle table: cw[j] = W32^{2j} on lanes<32, W32^{2j+1} on lanes>=32
    f2 cwA[8], cwB[8];
#pragma unroll
    for (int j = 0; j < 8; ++j) {
        cwA[j] = hi ? (f2){W32C[2 * j + 1], W32S[2 * j + 1]}
                    : (f2){W32C[2 * j],     W32S[2 * j]};
        cwB[j] = (f2){-cwA[j].y, cwA[j].x};
    }

    // dual-form twiddle tables for W_1024^{tau*k2}, k2=2m+b5
    f2 TA[8], TB[8], ThA, ThB;
    {
        float rev = -(float)tau * (1.0f / 1024.0f);   // revolutions (v_cos/v_sin input)
        f2 w  = (f2){__builtin_amdgcn_cosf(rev), __builtin_amdgcn_sinf(rev)};
        f2 w2 = csqrf(w);
        TA[0] = hi ? w : (f2){1.0f, 0.0f};
#pragma unroll
        for (int j = 1; j < 8; ++j) TA[j] = cmulf(TA[j - 1], w2);
        ThA = csqrf(csqrf(csqrf(w2)));                // w^16
#pragma unroll
        for (int j = 0; j < 8; ++j) TB[j] = (f2){-TA[j].y, TA[j].x};
        ThB = (f2){-ThA.y, ThA.x};
    }

    const float* pz0 = gr + (size_t)row0 * 1024 + gofs;
    const float* pz1 = gr + (size_t)row1 * 1024 + gofs;
    const float* px0 = gh + (size_t)row0 * 1024 + gofs;
    const float* px1 = gt + (size_t)row0 * 1024 + gofs;
    const float* py0 = gh + (size_t)row1 * 1024 + gofs;
    const float* py1 = gt + (size_t)row1 * 1024 + gofs;

    f2 z[16], x[16];

    // issue Z and X0 loads up front (latency hidden under Z's FFT)
#pragma unroll
    for (int k = 0; k < 16; ++k) z[k] = (f2){pz0[k * 32], pz1[k * 32]};
#pragma unroll
    for (int k = 0; k < 16; ++k) x[k] = (f2){px0[k * 32], px1[k * 32]};

    // ================= Z = FFT(r0 + i r1) =================
    fft32d(z, cwA, cwB);
#pragma unroll
    for (int rr = 0; rr < 16; ++rr) {               // twiddle W_1024^{tau*k2}
        const int m = br4(rr);
        f2 v = z[rr];
        if (m < 8) {
            z[rr] = v.x * TA[m] + v.y * TB[m];
        } else {
            f2 u = v.x * TA[m - 8] + v.y * TB[m - 8];
            z[rr] = u.x * ThA + u.y * ThB;
        }
    }
    __builtin_amdgcn_wave_barrier();
#pragma unroll
    for (int rr = 0; rr < 16; ++rr)
        *(f2*)(wp + 16 * br4(rr)) = z[rr];
    __builtin_amdgcn_wave_barrier();
#pragma unroll
    for (int k = 0; k < 16; ++k)
        z[k] = *(const f2*)(rp_ + 264 * k);
    fft32d(z, cwA, cwB);                             // z[rr] = Z at f = 32*(2*br4(rr)+b5)+tau

    // ================= X0 = FFT(h0 + i t0) =================
    fft32d(x, cwA, cwB);
#pragma unroll
    for (int rr = 0; rr < 16; ++rr) {
        const int m = br4(rr);
        f2 v = x[rr];
        if (m < 8) {
            x[rr] = v.x * TA[m] + v.y * TB[m];
        } else {
            f2 u = v.x * TA[m - 8] + v.y * TB[m - 8];
            x[rr] = u.x * ThA + u.y * ThB;
        }
    }
    __builtin_amdgcn_wave_barrier();
#pragma unroll
    for (int rr = 0; rr < 16; ++rr)
        *(f2*)(wp + 16 * br4(rr)) = x[rr];
    __builtin_amdgcn_wave_barrier();
#pragma unroll
    for (int k = 0; k < 16; ++k)
        x[k] = *(const f2*)(rp_ + 264 * k);
    fft32d(x, cwA, cwB);

    // score0 = sum_f 2*im*Z.x - dm*Z.y   (Z lane-local; identity R7-verified)
    float acc0 = 0.0f;
#pragma unroll
    for (int rr = 0; rr < 16; ++rr) {
        const int rq = 15 - rr;
        const int rs = br4((16 - br4(rr)) & 15);
        float fx = __shfl(x[rq].x, pl, 64);
        float fy = __shfl(x[rq].y, pl, 64);
        fx = fix0 ? x[rs].x : fx;
        fy = fix0 ? x[rs].y : fy;
        float im = x[rr].x * fy + x[rr].y * fx;                       // Im(X_f X_-f)
        float dm = fmaf(x[rr].x, x[rr].x, x[rr].y * x[rr].y)
                 - fmaf(fx, fx, fy * fy);                             // |X_f|^2-|X_-f|^2
        acc0 = fmaf(2.0f * im, z[rr].x, acc0);
        acc0 = fmaf(-dm,       z[rr].y, acc0);
    }

    // ================= X1 = FFT(h1 + i t1), reusing x registers =================
#pragma unroll
    for (int k = 0; k < 16; ++k) x[k] = (f2){py0[k * 32], py1[k * 32]};

    fft32d(x, cwA, cwB);
#pragma unroll
    for (int rr = 0; rr < 16; ++rr) {
        const int m = br4(rr);
        f2 v = x[rr];
        if (m < 8) {
            x[rr] = v.x * TA[m] + v.y * TB[m];
        } else {
            f2 u = v.x * TA[m - 8] + v.y * TB[m - 8];
            x[rr] = u.x * ThA + u.y * ThB;
        }
    }
    __builtin_amdgcn_wave_barrier();
#pragma unroll
    for (int rr = 0; rr < 16; ++rr)
        *(f2*)(wp + 16 * br4(rr)) = x[rr];
    __builtin_amdgcn_wave_barrier();
#pragma unroll
    for (int k = 0; k < 16; ++k)
        x[k] = *(const f2*)(rp_ + 264 * k);
    fft32d(x, cwA, cwB);

    // score1 = sum_f 2*im*Z.y + dm*Z.x
    float acc1 = 0.0f;
#pragma unroll
    for (int rr = 0; rr < 16; ++rr) {
        const int rq = 15 - rr;
        const int rs = br4((16 - br4(rr)) & 15);
        float fx = __shfl(x[rq].x, pl, 64);
        float fy = __shfl(x[rq].y, pl, 64);
        fx = fix0 ? x[rs].x : fx;
        fy = fix0 ? x[rs].y : fy;
        float im = x[rr].x * fy + x[rr].y * fx;
        float dm = fmaf(x[rr].x, x[rr].x, x[rr].y * x[rr].y)
                 - fmaf(fx, fx, fy * fy);
        acc1 = fmaf(2.0f * im, z[rr].y, acc1);
        acc1 = fmaf(dm,        z[rr].x, acc1);
    }

    // cross-32 reduce of BOTH accs with one swap: lane0 -> row0, lane32 -> row1
    pl32swap(acc0, acc1);
    float s = acc0 + acc1;
#pragma unroll
    for (int off = 16; off > 0; off >>= 1)
        s += __shfl_xor(s, off, 64);
    if (tau == 0)
        out[row0 + b5] = s * (1.0f / 4096.0f);

    (void)hi;
}

extern "C" void kernel_launch(void* const* d_in, const int* in_sizes, int n_in,
                              void* d_out, int out_size, void* d_ws, size_t ws_size,
                              hipStream_t stream) {
    const float* h = (const float*)d_in[0];
    const float* r = (const float*)d_in[1];
    const float* t = (const float*)d_in[2];
    float* out = (float*)d_out;
    int nblocks = out_size / 4;   // 2 row-pairs per block
    hipLaunchKernelGGL(hole_fft_kernel, dim3(nblocks), dim3(NT), 0, stream,
                       h, r, t, out);
}

// Round 15
// 313.434 us; speedup vs baseline: 1.0999x; 1.0036x over previous
//
#include <hip/hip_runtime.h>

#define NT 128   // 2 waves/block: 16896 B LDS/block -> 9 blocks/CU (R13-verified best)

typedef float f2 __attribute__((ext_vector_type(2)));

// 4-bit bit-reversal (involution)
constexpr int br4(int i) {
    return ((i & 1) << 3) | ((i & 2) << 1) | ((i & 4) >> 1) | ((i & 8) >> 3);
}

// W_32^j = e^{-2*pi*i*j/32}
__device__ constexpr float W32C[16] = {
    1.0f,                0.980785280403230f,  0.923879532511287f,  0.831469612302545f,
    0.707106781186548f,  0.555570233019602f,  0.382683432365090f,  0.195090322016128f,
    0.0f,               -0.195090322016128f, -0.382683432365090f, -0.555570233019602f,
   -0.707106781186548f, -0.831469612302545f, -0.923879532511287f, -0.980785280403230f};
__device__ constexpr float W32S[16] = {
   -0.0f,               -0.195090322016128f, -0.382683432365090f, -0.555570233019602f,
   -0.707106781186548f, -0.831469612302545f, -0.923879532511287f, -0.980785280403230f,
   -1.0f,               -0.980785280403230f, -0.923879532511287f, -0.831469612302545f,
   -0.707106781186548f, -0.555570233019602f, -0.382683432365090f, -0.195090322016128f};

// One-instruction half-wave exchange: a.hi <-> b.lo  (VALU crosslane, not DS pipe)
__device__ __forceinline__ void pl32swap(float& a, float& b) {
    asm("v_permlane32_swap_b32 %0, %1" : "+v"(a), "+v"(b));
}

__device__ __forceinline__ f2 cmulf(f2 a, f2 b) {
    return (f2){a.x * b.x - a.y * b.y, a.x * b.y + a.y * b.x};
}
__device__ __forceinline__ f2 csqrf(f2 a) {
    return (f2){a.x * a.x - a.y * a.y, 2.0f * a.x * a.y};
}

// In-register 16-pt radix-2 DIF FFT (pk-friendly). Output: v[r] = X[br4(r)].
__device__ __forceinline__ void fft16(f2 (&v)[16]) {
#pragma unroll
    for (int s = 8; s >= 1; s >>= 1) {
#pragma unroll
        for (int base = 0; base < 16; base += 2 * s) {
#pragma unroll
            for (int j = 0; j < s; ++j) {
                f2 u = v[base + j];
                f2 w = v[base + j + s];
                f2 d = u - w;
                v[base + j] = u + w;
                const int ti = j * (8 / s);
                if (ti == 0)
                    v[base + j + s] = d;
                else if (ti == 4)
                    v[base + j + s] = (f2){d.y, -d.x};
                else {
                    const f2 wa = {W32C[2 * ti], W32S[2 * ti]};
                    const f2 wb = {-W32S[2 * ti], W32C[2 * ti]};
                    v[base + j + s] = d.x * wa + d.y * wb;
                }
            }
        }
    }
}

// Distributed 32-pt FFT across lane-pair (lane, lane^32) via permlane32_swap,
// with the high-half twiddle FUSED into the D-path. R10/R13-hardware-verified.
// Entry: reg r holds y[r + 16*b5]. Exit: reg r holds Y[2*br4(r) + b5].
__device__ __forceinline__ void fft32d(f2 (&v)[16], const f2 (&cwA)[8], const f2 (&cwB)[8]) {
#pragma unroll
    for (int p = 0; p < 16; p += 2) {
        float ax = v[p].x,     ay = v[p].y;
        float bx = v[p + 1].x, by = v[p + 1].y;
        pl32swap(ax, bx);
        pl32swap(ay, by);
        f2 A = (f2){ax, ay};
        f2 B = (f2){bx, by};
        f2 S = A + B;
        f2 D = A - B;
        f2 Dt = D.x * cwA[p >> 1] + D.y * cwB[p >> 1];   // fused hi-twiddle
        float sx = S.x, sy = S.y, dx = Dt.x, dy = Dt.y;
        pl32swap(sx, dx);
        pl32swap(sy, dy);
        v[p]     = (f2){sx, sy};
        v[p + 1] = (f2){dx, dy};
    }
    fft16(v);
}

__global__ __launch_bounds__(NT) void hole_fft_kernel(
    const float* __restrict__ gh, const float* __restrict__ gr, const float* __restrict__ gt,
    float* __restrict__ out)
{
    __shared__ f2 lds[2 * 32 * 33];   // padded stride-33 rows: 8448 B/wave

    const int tid  = threadIdx.x;
    const int wv   = tid >> 6;
    const int lane = tid & 63;
    const int b5   = lane >> 5;
    const int tau  = lane & 31;
    const bool hi  = (b5 != 0);
    const bool fix0 = (lane == 0);   // only lane 0 needs the rs fixup (R7-verified)

    const int pairIdx = blockIdx.x * 2 + wv;
    const int row0 = pairIdx * 2, row1 = row0 + 1;
    const int gofs = tau + (b5 << 9);          // element n = gofs + 32*k

    // ---- issue Z and X0 loads FIRST: cold-start latency hides under the ~50-inst
    //      twiddle-table construction below (semantics-preserving code motion) ----
    const float* pz0 = gr + (size_t)row0 * 1024 + gofs;
    const float* pz1 = gr + (size_t)row1 * 1024 + gofs;
    const float* px0 = gh + (size_t)row0 * 1024 + gofs;
    const float* px1 = gt + (size_t)row0 * 1024 + gofs;
    const float* py0 = gh + (size_t)row1 * 1024 + gofs;
    const float* py1 = gt + (size_t)row1 * 1024 + gofs;

    f2 z[16], x[16];
#pragma unroll
    for (int k = 0; k < 16; ++k) z[k] = (f2){pz0[k * 32], pz1[k * 32]};
#pragma unroll
    for (int k = 0; k < 16; ++k) x[k] = (f2){px0[k * 32], px1[k * 32]};

    // padded transpose addressing: elem(row,col) at byte 264*row + 8*col (all-imm offsets)
    char* ldsB = (char*)lds + wv * 8448;
    char* wp   = ldsB + 264 * tau + 8 * b5;    // + 16*br4(rr) imm
    char* rp_  = ldsB + 4224 * b5 + 8 * tau;   // + 264*k imm

    const int pl = (tau == 0) ? lane : (((lane & 32) ^ 32) | (32 - tau));  // f<->-f partner

    // fused butterfly twiddle table: cw[j] = W32^{2j} on lanes<32, W32^{2j+1} on lanes>=32
    f2 cwA[8], cwB[8];
#pragma unroll
    for (int j = 0; j < 8; ++j) {
        cwA[j] = hi ? (f2){W32C[2 * j + 1], W32S[2 * j + 1]}
                    : (f2){W32C[2 * j],     W32S[2 * j]};
        cwB[j] = (f2){-cwA[j].y, cwA[j].x};
    }

    // dual-form twiddle tables for W_1024^{tau*k2}, k2=2m+b5
    f2 TA[8], TB[8], ThA, ThB;
    {
        float rev = -(float)tau * (1.0f / 1024.0f);
        f2 w  = (f2){__builtin_amdgcn_cosf(rev), __builtin_amdgcn_sinf(rev)};
        f2 w2 = csqrf(w);
        TA[0] = hi ? w : (f2){1.0f, 0.0f};
#pragma unroll
        for (int j = 1; j < 8; ++j) TA[j] = cmulf(TA[j - 1], w2);
        ThA = csqrf(csqrf(csqrf(w2)));                // w^16
#pragma unroll
        for (int j = 0; j < 8; ++j) TB[j] = (f2){-TA[j].y, TA[j].x};
        ThB = (f2){-ThA.y, ThA.x};
    }

    // ================= Z = FFT(r0 + i r1) =================
    fft32d(z, cwA, cwB);
#pragma unroll
    for (int rr = 0; rr < 16; ++rr) {
        const int m = br4(rr);
        f2 v = z[rr];
        if (m < 8) {
            z[rr] = v.x * TA[m] + v.y * TB[m];
        } else {
            f2 u = v.x * TA[m - 8] + v.y * TB[m - 8];
            z[rr] = u.x * ThA + u.y * ThB;
        }
    }
    __builtin_amdgcn_wave_barrier();
#pragma unroll
    for (int rr = 0; rr < 16; ++rr)
        *(f2*)(wp + 16 * br4(rr)) = z[rr];
    __builtin_amdgcn_wave_barrier();
#pragma unroll
    for (int k = 0; k < 16; ++k)
        z[k] = *(const f2*)(rp_ + 264 * k);
    fft32d(z, cwA, cwB);                             // z[rr] = Z at f = 32*(2*br4(rr)+b5)+tau

    // ================= X0 = FFT(h0 + i t0) =================
    fft32d(x, cwA, cwB);
#pragma unroll
    for (int rr = 0; rr < 16; ++rr) {
        const int m = br4(rr);
        f2 v = x[rr];
        if (m < 8) {
            x[rr] = v.x * TA[m] + v.y * TB[m];
        } else {
            f2 u = v.x * TA[m - 8] + v.y * TB[m - 8];
            x[rr] = u.x * ThA + u.y * ThB;
        }
    }
    __builtin_amdgcn_wave_barrier();
#pragma unroll
    for (int rr = 0; rr < 16; ++rr)
        *(f2*)(wp + 16 * br4(rr)) = x[rr];
    __builtin_amdgcn_wave_barrier();
#pragma unroll
    for (int k = 0; k < 16; ++k)
        x[k] = *(const f2*)(rp_ + 264 * k);
    fft32d(x, cwA, cwB);

    // score0 = sum_f 2*im*Z.x - dm*Z.y   (Z lane-local; identity R7-verified)
    float acc0 = 0.0f;
#pragma unroll
    for (int rr = 0; rr < 16; ++rr) {
        const int rq = 15 - rr;
        const int rs = br4((16 - br4(rr)) & 15);
        float fx = __shfl(x[rq].x, pl, 64);
        float fy = __shfl(x[rq].y, pl, 64);
        fx = fix0 ? x[rs].x : fx;
        fy = fix0 ? x[rs].y : fy;
        float im = x[rr].x * fy + x[rr].y * fx;                       // Im(X_f X_-f)
        float dm = fmaf(x[rr].x, x[rr].x, x[rr].y * x[rr].y)
                 - fmaf(fx, fx, fy * fy);                             // |X_f|^2-|X_-f|^2
        acc0 = fmaf(2.0f * im, z[rr].x, acc0);
        acc0 = fmaf(-dm,       z[rr].y, acc0);
    }

    // ================= X1 = FFT(h1 + i t1), reusing x registers =================
#pragma unroll
    for (int k = 0; k < 16; ++k) x[k] = (f2){py0[k * 32], py1[k * 32]};

    fft32d(x, cwA, cwB);
#pragma unroll
    for (int rr = 0; rr < 16; ++rr) {
        const int m = br4(rr);
        f2 v = x[rr];
        if (m < 8) {
            x[rr] = v.x * TA[m] + v.y * TB[m];
        } else {
            f2 u = v.x * TA[m - 8] + v.y * TB[m - 8];
            x[rr] = u.x * ThA + u.y * ThB;
        }
    }
    __builtin_amdgcn_wave_barrier();
#pragma unroll
    for (int rr = 0; rr < 16; ++rr)
        *(f2*)(wp + 16 * br4(rr)) = x[rr];
    __builtin_amdgcn_wave_barrier();
#pragma unroll
    for (int k = 0; k < 16; ++k)
        x[k] = *(const f2*)(rp_ + 264 * k);
    fft32d(x, cwA, cwB);

    // score1 = sum_f 2*im*Z.y + dm*Z.x
    float acc1 = 0.0f;
#pragma unroll
    for (int rr = 0; rr < 16; ++rr) {
        const int rq = 15 - rr;
        const int rs = br4((16 - br4(rr)) & 15);
        float fx = __shfl(x[rq].x, pl, 64);
        float fy = __shfl(x[rq].y, pl, 64);
        fx = fix0 ? x[rs].x : fx;
        fy = fix0 ? x[rs].y : fy;
        float im = x[rr].x * fy + x[rr].y * fx;
        float dm = fmaf(x[rr].x, x[rr].x, x[rr].y * x[rr].y)
                 - fmaf(fx, fx, fy * fy);
        acc1 = fmaf(2.0f * im, z[rr].y, acc1);
        acc1 = fmaf(dm,        z[rr].x, acc1);
    }

    // cross-32 reduce of BOTH accs with one swap: lane0 -> row0, lane32 -> row1
    pl32swap(acc0, acc1);
    float s = acc0 + acc1;
#pragma unroll
    for (int off = 16; off > 0; off >>= 1)
        s += __shfl_xor(s, off, 64);
    if (tau == 0)
        out[row0 + b5] = s * (1.0f / 4096.0f);

    (void)hi;
}

extern "C" void kernel_launch(void* const* d_in, const int* in_sizes, int n_in,
                              void* d_out, int out_size, void* d_ws, size_t ws_size,
                              hipStream_t stream) {
    const float* h = (const float*)d_in[0];
    const float* r = (const float*)d_in[1];
    const float* t = (const float*)d_in[2];
    float* out = (float*)d_out;
    int nblocks = out_size / 4;   // 2 row-pairs per block
    hipLaunchKernelGGL(hole_fft_kernel, dim3(nblocks), dim3(NT), 0, stream,
                       h, r, t, out);
}